// Round 5
// baseline (3373.031 us; speedup 1.0000x reference)
//
#include <hip/hip_runtime.h>
#include <hip/hip_bf16.h>
#include <cstdint>

using bf16 = __hip_bfloat16;

static constexpr int B = 2;
static constexpr int N = 2048;
static constexpr int KNN = 32;
static constexpr int FD = 480;
static constexpr float EPS = 1e-5f;
static constexpr float SLOPE = 0.2f;

__device__ __forceinline__ float lrelu(float x) { return x >= 0.f ? x : SLOPE * x; }

// ---------------------------------------------------------------- dtype sniff
__global__ void sniff_kernel(const unsigned short* __restrict__ xr, int nelem,
                             int* __restrict__ flag) {
  __shared__ float red[256];
  float mx = 0.f;
  for (int i = threadIdx.x; i < nelem; i += 256) {
    float v = __uint_as_float(((unsigned)xr[i]) << 16);
    v = fabsf(v);
    if (!(v < 1e30f)) v = 1e30f;  // NaN/inf -> huge
    mx = fmaxf(mx, v);
  }
  red[threadIdx.x] = mx;
  __syncthreads();
  for (int s = 128; s > 0; s >>= 1) {
    if (threadIdx.x < s) red[threadIdx.x] = fmaxf(red[threadIdx.x], red[threadIdx.x + s]);
    __syncthreads();
  }
  if (threadIdx.x == 0) flag[0] = (red[0] > 1e3f) ? 1 : 0;
}

__device__ __forceinline__ float load_in(const void* p, int i, int isf32) {
  return isf32 ? ((const float*)p)[i] : __bfloat162float(((const bf16*)p)[i]);
}

// ---------------------------------------------------------------- prep
__global__ void convert_kernel(const void* __restrict__ x, float* __restrict__ xf, int n,
                               const int* __restrict__ flag) {
  int i = blockIdx.x * 256 + threadIdx.x;
  int isf = flag[0];
  if (i < n) xf[i] = load_in(x, i, isf);
}

// W [O][IC] -> Wt [IC][O] (fp32)
__global__ void transpose_w_kernel(const void* __restrict__ W, float* __restrict__ Wt,
                                   int O, int IC, const int* __restrict__ flag) {
  int i = blockIdx.x * 256 + threadIdx.x;
  int isf = flag[0];
  if (i < O * IC) {
    int o = i / IC, c = i - o * IC;
    Wt[c * O + o] = load_in(W, i, isf);
  }
}

// ---------------------------------------------------------------- knn
__global__ void sq_kernel(const float* __restrict__ h, int stride, int C,
                          float* __restrict__ sqv) {
  int i = blockIdx.x * 256 + threadIdx.x;  // b*N + n
  const float* r = h + (size_t)i * stride;
  float s = 0.f;
  for (int c = 0; c < C; ++c) s += r[c] * r[c];
  sqv[i] = s;
}

// 128x128 output tile per block, 8x8 per thread, channel-major LDS (b128 reads).
template <int C>
__global__ __launch_bounds__(256) void dist_kernel(const float* __restrict__ h, int hstride,
                                                   const float* __restrict__ sqv,
                                                   float* __restrict__ dist) {
  constexpr int CW = 16;
  __shared__ float Ast[CW][132];
  __shared__ float Bst[CW][132];
  int b = blockIdx.z;
  int n0 = blockIdx.y * 128, m0 = blockIdx.x * 128;
  int tid = threadIdx.x;
  int tx = tid & 15, ty = tid >> 4;
  float dot[8][8] = {};
  for (int cc = 0; cc < C; cc += CW) {
    for (int i = tid; i < 128 * CW; i += 256) {
      int c = i & 15, r = i >> 4;
      int gc = cc + c;
      float av = 0.f, bv = 0.f;
      if (gc < C) {
        av = h[(size_t)(b * N + n0 + r) * hstride + gc];
        bv = h[(size_t)(b * N + m0 + r) * hstride + gc];
      }
      Ast[c][r] = av;
      Bst[c][r] = bv;
    }
    __syncthreads();
#pragma unroll
    for (int c = 0; c < CW; ++c) {
      float av[8], bv[8];
      *reinterpret_cast<float4*>(&av[0]) = *reinterpret_cast<const float4*>(&Ast[c][ty * 8]);
      *reinterpret_cast<float4*>(&av[4]) = *reinterpret_cast<const float4*>(&Ast[c][ty * 8 + 4]);
      *reinterpret_cast<float4*>(&bv[0]) = *reinterpret_cast<const float4*>(&Bst[c][tx * 8]);
      *reinterpret_cast<float4*>(&bv[4]) = *reinterpret_cast<const float4*>(&Bst[c][tx * 8 + 4]);
#pragma unroll
      for (int i = 0; i < 8; ++i)
#pragma unroll
        for (int j = 0; j < 8; ++j) dot[i][j] += av[i] * bv[j];
    }
    __syncthreads();
  }
#pragma unroll
  for (int i = 0; i < 8; ++i) {
    int nn = n0 + ty * 8 + i;
    float sn = sqv[b * N + nn];
#pragma unroll
    for (int jq = 0; jq < 2; ++jq) {
      float4 w;
      w.x = sn + sqv[b * N + m0 + tx * 8 + jq * 4 + 0] - 2.f * dot[i][jq * 4 + 0];
      w.y = sn + sqv[b * N + m0 + tx * 8 + jq * 4 + 1] - 2.f * dot[i][jq * 4 + 1];
      w.z = sn + sqv[b * N + m0 + tx * 8 + jq * 4 + 2] - 2.f * dot[i][jq * 4 + 2];
      w.w = sn + sqv[b * N + m0 + tx * 8 + jq * 4 + 3] - 2.f * dot[i][jq * 4 + 3];
      *reinterpret_cast<float4*>(&dist[(size_t)(b * N + nn) * N + m0 + tx * 8 + jq * 4]) = w;
    }
  }
}

__device__ __forceinline__ unsigned long long wave_min_u64(unsigned long long v) {
#pragma unroll
  for (int m = 1; m < 64; m <<= 1) {
    unsigned lo = (unsigned)v;
    unsigned hi = (unsigned)(v >> 32);
    unsigned olo = (unsigned)__shfl_xor((int)lo, m, 64);
    unsigned ohi = (unsigned)__shfl_xor((int)hi, m, 64);
    unsigned long long ov = ((unsigned long long)ohi << 32) | olo;
    if (ov < v) v = ov;
  }
  return v;
}

// One wave per row: lane caches 32 keys in registers, 33 extract-min rounds.
__global__ __launch_bounds__(256) void select_kernel(const float* __restrict__ dist,
                                                     int* __restrict__ idxb) {
  int row = blockIdx.x * 4 + (threadIdx.x >> 6);  // b*N + n
  int lane = threadIdx.x & 63;
  const float* drow = dist + (size_t)row * N;
  unsigned long long key[32];
#pragma unroll
  for (int j = 0; j < 32; ++j) {
    int m = j * 64 + lane;
    unsigned u = __float_as_uint(drow[m]);
    u = (u & 0x80000000u) ? ~u : (u | 0x80000000u);
    key[j] = ((unsigned long long)u << 32) | (unsigned)m;
  }
  unsigned long long lmin = key[0];
#pragma unroll
  for (int j = 1; j < 32; ++j) lmin = key[j] < lmin ? key[j] : lmin;
  unsigned saved = 0;
  for (int it = 0; it <= KNN; ++it) {
    unsigned long long gmin = wave_min_u64(lmin);
    if (it > 0 && lane == it - 1) saved = (unsigned)(gmin & 0xFFFFFFFFull);
    if (lmin == gmin) {  // unique keys -> exactly one winner lane
#pragma unroll
      for (int j = 0; j < 32; ++j)
        if (key[j] == gmin) key[j] = ~0ull;
      lmin = key[0];
#pragma unroll
      for (int j = 1; j < 32; ++j) lmin = key[j] < lmin ? key[j] : lmin;
    }
  }
  if (lane < KNN) idxb[row * KNN + lane] = (int)saved;
}

// ---------------------------------------------------------------- edge conv (fused)
// e[k][o] = sum_c Wd[c][o]*(nbr[k][c]-cen[c]) + sigma[o],
// sigma[o] = sum_c Wcen[c][o]*cen[c].
// Thread tile: OT=O/32 outputs x 4 k (k = 8j+ko). nbr from LDS (b128,
// conflict-free), weights from global/L2. Writes max over k into feats slice,
// channel sum/sumsq via atomics.
template <int C, int O>
__global__ __launch_bounds__(256) void edge_kernel(const float* __restrict__ h, int hstride,
                                                   const int* __restrict__ idxb,
                                                   const float* __restrict__ Wt,  // [2C][O]
                                                   float* __restrict__ cstats,    // [B*O*2]
                                                   float* __restrict__ featdst) { // feats col slice
  constexpr int OT = O / 32;
  constexpr int CP = (C % 4 == 0) ? C + 4 : C + 1;
  int bn = blockIdx.x;
  int b = bn >> 11;
  int tid = threadIdx.x;
  int ko = tid & 7;
  int og = tid >> 3;
  int o0 = og * OT;

  __shared__ float nbr[KNN][CP];
  __shared__ float cen[C];
  __shared__ int knn[KNN];

  const float* hrow = h + (size_t)bn * hstride;
  if (tid < C) cen[tid] = hrow[tid];
  if (tid < KNN) knn[tid] = idxb[bn * KNN + tid];
  __syncthreads();
  for (int i = tid; i < KNN * C; i += 256) {
    int k = i / C, c = i - k * C;
    nbr[k][c] = h[(size_t)(b * N + knn[k]) * hstride + c] - cen[c];
  }
  __syncthreads();

  // sigma, cooperative over the 8 ko lanes of each og group
  float sig[OT] = {};
  for (int c = ko; c < C; c += 8) {
    float cv = cen[c];
    const float* wrow = Wt + (size_t)(C + c) * O + o0;
#pragma unroll
    for (int ot = 0; ot < OT; ++ot) sig[ot] += wrow[ot] * cv;
  }
#pragma unroll
  for (int ot = 0; ot < OT; ++ot) {
#pragma unroll
    for (int m = 1; m < 8; m <<= 1) sig[ot] += __shfl_xor(sig[ot], m, 64);
  }

  float acc[4][OT];
#pragma unroll
  for (int j = 0; j < 4; ++j)
#pragma unroll
    for (int ot = 0; ot < OT; ++ot) acc[j][ot] = sig[ot];

  if constexpr (C % 4 == 0) {
    for (int c = 0; c < C; c += 4) {
      float4 v[4];
#pragma unroll
      for (int j = 0; j < 4; ++j)
        v[j] = *reinterpret_cast<const float4*>(&nbr[j * 8 + ko][c]);
#pragma unroll
      for (int i = 0; i < 4; ++i) {
        const float* wrow = Wt + (size_t)(c + i) * O + o0;
        float w[OT];
        if constexpr (OT >= 4) {
#pragma unroll
          for (int q = 0; q < OT / 4; ++q)
            *reinterpret_cast<float4*>(&w[q * 4]) =
                *reinterpret_cast<const float4*>(&wrow[q * 4]);
        } else if constexpr (OT == 2) {
          w[0] = wrow[0];
          w[1] = wrow[1];
        } else {
          w[0] = wrow[0];
        }
#pragma unroll
        for (int j = 0; j < 4; ++j) {
          const float* vp = &v[j].x;
          float vv = vp[i];
#pragma unroll
          for (int ot = 0; ot < OT; ++ot) acc[j][ot] += w[ot] * vv;
        }
      }
    }
  } else {
    for (int c = 0; c < C; ++c) {
      float v[4];
#pragma unroll
      for (int j = 0; j < 4; ++j) v[j] = nbr[j * 8 + ko][c];
      const float* wrow = Wt + (size_t)c * O + o0;
      float w[OT];
#pragma unroll
      for (int ot = 0; ot < OT; ++ot) w[ot] = wrow[ot];
#pragma unroll
      for (int j = 0; j < 4; ++j)
#pragma unroll
        for (int ot = 0; ot < OT; ++ot) acc[j][ot] += w[ot] * v[j];
    }
  }

#pragma unroll
  for (int ot = 0; ot < OT; ++ot) {
    float s = 0.f, ss = 0.f, mx = -3.4e38f;
#pragma unroll
    for (int j = 0; j < 4; ++j) {
      float e = acc[j][ot];
      s += e;
      ss += e * e;
      mx = fmaxf(mx, e);
    }
#pragma unroll
    for (int m = 1; m < 8; m <<= 1) {
      s += __shfl_xor(s, m, 64);
      ss += __shfl_xor(ss, m, 64);
      mx = fmaxf(mx, __shfl_xor(mx, m, 64));
    }
    if (ko == 0) {
      atomicAdd(&cstats[(b * O + o0 + ot) * 2 + 0], s);
      atomicAdd(&cstats[(b * O + o0 + ot) * 2 + 1], ss);
      featdst[(size_t)bn * FD + o0 + ot] = mx;
    }
  }
}

// in-place: featdst = lrelu((featdst - mean) * rsqrt(var + eps))
__global__ void finalize_kernel(const float* __restrict__ cstats,
                                float* __restrict__ featdst, int O) {
  int i = blockIdx.x * 256 + threadIdx.x;  // (b*N+n)*O + o
  int o = i % O;
  int bn = i / O;
  int b = bn >> 11;
  float s = cstats[(b * O + o) * 2 + 0];
  float ss = cstats[(b * O + o) * 2 + 1];
  constexpr float inv = 1.f / ((float)N * KNN);
  float m = s * inv;
  float v = fmaxf(ss * inv - m * m, 0.f);
  float* p = &featdst[(size_t)bn * FD + o];
  float e = (*p - m) * rsqrtf(v + EPS);
  *p = lrelu(e);
}

// ---------------------------------------------------------------- 480 -> 128 stage
__global__ __launch_bounds__(256) void fstage_kernel(const float* __restrict__ feats,
                                                     const float* __restrict__ Wht,  // [480][128]
                                                     float* __restrict__ fsum,
                                                     float* __restrict__ fss,
                                                     unsigned* __restrict__ fmaxu) {
  int blk = blockIdx.x;
  int b = blk >> 7;
  int n0 = (blk & 127) * 16;
  int tid = threadIdx.x;
  __shared__ float rows[16][FD];
  __shared__ float red[3][2][128];
  for (int i = tid; i < 16 * FD; i += 256) {
    int r = i / FD, c = i - r * FD;
    rows[r][c] = feats[(size_t)(b * N + n0 + r) * FD + c];
  }
  __syncthreads();
  int o = tid & 127, g = tid >> 7;
  float acc[8] = {};
  for (int c = 0; c < FD; ++c) {
    float w = Wht[c * 128 + o];
#pragma unroll
    for (int j = 0; j < 8; ++j) acc[j] += w * rows[g * 8 + j][c];
  }
  float s = 0.f, ss = 0.f, mx = -3.4e38f;
#pragma unroll
  for (int j = 0; j < 8; ++j) {
    float f = acc[j];
    s += f;
    ss += f * f;
    mx = fmaxf(mx, f);
  }
  red[0][g][o] = s;
  red[1][g][o] = ss;
  red[2][g][o] = mx;
  __syncthreads();
  if (g == 0) {
    s += red[0][1][o];
    ss += red[1][1][o];
    mx = fmaxf(mx, red[2][1][o]);
    atomicAdd(&fsum[b * 128 + o], s);
    atomicAdd(&fss[b * 128 + o], ss);
    unsigned u = __float_as_uint(mx);
    u = (u & 0x80000000u) ? ~u : (u | 0x80000000u);
    atomicMax(&fmaxu[b * 128 + o], u);
  }
}

// ---------------------------------------------------------------- head
__global__ __launch_bounds__(128) void head_kernel(const float* __restrict__ fsum,
                                                   const float* __restrict__ fss,
                                                   const unsigned* __restrict__ fmaxu,
                                                   const float* __restrict__ fc1w,
                                                   const float* __restrict__ fc1b,
                                                   const float* __restrict__ fc2w,
                                                   const float* __restrict__ fc2b,
                                                   void* __restrict__ out,
                                                   const int* __restrict__ flag) {
  int b = blockIdx.x, o = threadIdx.x;
  __shared__ float gs[128], t1[128], ys[128];
  constexpr float invN = 1.f / N;
  float m = fsum[b * 128 + o] * invN;
  float v = fmaxf(fss[b * 128 + o] * invN - m * m, 0.f);
  unsigned u = fmaxu[b * 128 + o];
  unsigned bits = (u & 0x80000000u) ? (u ^ 0x80000000u) : ~u;
  float fx = __uint_as_float(bits);
  gs[o] = lrelu((fx - m) * rsqrtf(v + EPS));
  __syncthreads();
  float a = fc1b[o];
  for (int c = 0; c < 128; ++c) a += fc1w[o * 128 + c] * gs[c];
  t1[o] = a;
  __syncthreads();
  float mm = 0.f;
  for (int c = 0; c < 128; ++c) mm += t1[c];
  mm *= (1.f / 128);
  float vv = 0.f;
  for (int c = 0; c < 128; ++c) {
    float d = t1[c] - mm;
    vv += d * d;
  }
  vv *= (1.f / 128);
  ys[o] = lrelu((a - mm) * rsqrtf(vv + EPS));
  __syncthreads();
  float r = fc2b[o];
  for (int c = 0; c < 128; ++c) r += fc2w[o * 128 + c] * ys[c];
  if (flag[0])
    ((float*)out)[b * 128 + o] = r;
  else
    ((bf16*)out)[b * 128 + o] = __float2bfloat16(r);
}

// ---------------------------------------------------------------- driver
template <int C, int O>
static void run_layer(const float* h, int hstride, float* featdst, const float* Wt,
                      float* cstats, float* sqv, float* dist, int* idxb,
                      hipStream_t stream) {
  sq_kernel<<<B * N / 256, 256, 0, stream>>>(h, hstride, C, sqv);
  dist_kernel<C><<<dim3(N / 128, N / 128, B), 256, 0, stream>>>(h, hstride, sqv, dist);
  select_kernel<<<B * N / 4, 256, 0, stream>>>(dist, idxb);
  edge_kernel<C, O><<<B * N, 256, 0, stream>>>(h, hstride, idxb, Wt, cstats, featdst);
  finalize_kernel<<<B * N * O / 256, 256, 0, stream>>>(cstats, featdst, O);
}

extern "C" void kernel_launch(void* const* d_in, const int* in_sizes, int n_in,
                              void* d_out, int out_size, void* d_ws, size_t ws_size,
                              hipStream_t stream) {
  const void* x = d_in[0];
  // d_in[1] = normals, unused (include_normals=False)
  const void* W0 = d_in[2];
  const void* W1 = d_in[3];
  const void* W2 = d_in[4];
  const void* W3 = d_in[5];
  const void* Wh = d_in[6];
  const void* fc1w = d_in[7];
  const void* fc1b = d_in[8];
  const void* fc2w = d_in[9];
  const void* fc2b = d_in[10];

  float* ws = (float*)d_ws;
  size_t off = 0;
  auto alloc = [&](size_t n) {
    float* p = ws + off;
    off += n;
    return p;
  };
  float* xf = alloc((size_t)B * N * 3);
  float* feats = alloc((size_t)B * N * FD);
  float* dist = alloc((size_t)B * N * N);
  float* sqv = alloc((size_t)B * N);
  int* idxb = (int*)alloc((size_t)B * N * KNN);
  float* wt0 = alloc(32 * 6);
  float* wt1 = alloc(64 * 64);
  float* wt2 = alloc(128 * 128);
  float* wt3 = alloc(256 * 256);
  float* wht = alloc(480 * 128);
  float* f1w = alloc(128 * 128);
  float* f1b = alloc(128);
  float* f2w = alloc(128 * 128);
  float* f2b = alloc(128);
  int* flag = (int*)alloc(64);
  float* zstart = ws + off;  // everything below is zero-initialized per launch
  float* cs0 = alloc(B * 32 * 2);
  float* cs1 = alloc(B * 64 * 2);
  float* cs2 = alloc(B * 128 * 2);
  float* cs3 = alloc(B * 256 * 2);
  float* fsum = alloc(B * 128);
  float* fss = alloc(B * 128);
  unsigned* fmaxu = (unsigned*)alloc(B * 128);
  size_t zbytes = (size_t)((ws + off) - zstart) * sizeof(float);

  hipMemsetAsync(zstart, 0, zbytes, stream);
  sniff_kernel<<<1, 256, 0, stream>>>((const unsigned short*)x, B * N * 3, flag);
  convert_kernel<<<(B * N * 3 + 255) / 256, 256, 0, stream>>>(x, xf, B * N * 3, flag);
  transpose_w_kernel<<<1, 256, 0, stream>>>(W0, wt0, 32, 6, flag);
  transpose_w_kernel<<<16, 256, 0, stream>>>(W1, wt1, 64, 64, flag);
  transpose_w_kernel<<<64, 256, 0, stream>>>(W2, wt2, 128, 128, flag);
  transpose_w_kernel<<<256, 256, 0, stream>>>(W3, wt3, 256, 256, flag);
  transpose_w_kernel<<<240, 256, 0, stream>>>(Wh, wht, 128, 480, flag);
  convert_kernel<<<64, 256, 0, stream>>>(fc1w, f1w, 128 * 128, flag);
  convert_kernel<<<1, 128, 0, stream>>>(fc1b, f1b, 128, flag);
  convert_kernel<<<64, 256, 0, stream>>>(fc2w, f2w, 128 * 128, flag);
  convert_kernel<<<1, 128, 0, stream>>>(fc2b, f2b, 128, flag);

  run_layer<3, 32>(xf, 3, feats + 0, wt0, cs0, sqv, dist, idxb, stream);
  run_layer<32, 64>(feats + 0, FD, feats + 32, wt1, cs1, sqv, dist, idxb, stream);
  run_layer<64, 128>(feats + 32, FD, feats + 96, wt2, cs2, sqv, dist, idxb, stream);
  run_layer<128, 256>(feats + 96, FD, feats + 224, wt3, cs3, sqv, dist, idxb, stream);

  fstage_kernel<<<B * 128, 256, 0, stream>>>(feats, wht, fsum, fss, fmaxu);
  head_kernel<<<B, 128, 0, stream>>>(fsum, fss, fmaxu, f1w, f1b, f2w, f2b, d_out, flag);
}

// Round 6
// 3241.245 us; speedup vs baseline: 1.0407x; 1.0407x over previous
//
#include <hip/hip_runtime.h>
#include <hip/hip_bf16.h>
#include <cstdint>

using bf16 = __hip_bfloat16;

static constexpr int B = 2;
static constexpr int N = 2048;
static constexpr int KNN = 32;
static constexpr int FD = 480;
static constexpr float EPS = 1e-5f;
static constexpr float SLOPE = 0.2f;

// ---------------- workspace layout (floats), all compile-time ----------------
static constexpr size_t N_XF = (size_t)B * N * 3;        // 12288
static constexpr size_t N_FEATS = (size_t)B * N * FD;    // 1966080
static constexpr size_t N_DIST = (size_t)B * N * N;      // 8388608
static constexpr size_t N_IDX = (size_t)B * N * KNN;     // 131072
static constexpr size_t O_XF = 0;
static constexpr size_t O_FEATS = O_XF + N_XF;
static constexpr size_t O_DIST = O_FEATS + N_FEATS;
static constexpr size_t O_IDX = O_DIST + N_DIST;
static constexpr size_t O_WT0 = O_IDX + N_IDX;
static constexpr size_t O_WT1 = O_WT0 + 192;
static constexpr size_t O_WT2 = O_WT1 + 4096;
static constexpr size_t O_WT3 = O_WT2 + 16384;
static constexpr size_t O_WHT = O_WT3 + 65536;
static constexpr size_t O_F1W = O_WHT + 61440;
static constexpr size_t O_F1B = O_F1W + 16384;
static constexpr size_t O_F2W = O_F1B + 128;
static constexpr size_t O_F2B = O_F2W + 16384;
static constexpr size_t O_FLAG = O_F2B + 128;
static constexpr size_t O_CS0 = O_FLAG + 16;   // zero region starts here
static constexpr size_t O_CS1 = O_CS0 + 128;
static constexpr size_t O_CS2 = O_CS1 + 256;
static constexpr size_t O_CS3 = O_CS2 + 512;
static constexpr size_t O_FSUM = O_CS3 + 1024;
static constexpr size_t O_FSS = O_FSUM + 256;
static constexpr size_t O_FMAX = O_FSS + 256;
static constexpr size_t O_END = O_FMAX + 256;
static constexpr size_t N_ZERO = O_END - O_CS0;  // 2688

__device__ __forceinline__ float lrelu(float x) { return x >= 0.f ? x : SLOPE * x; }

__device__ __forceinline__ float load_in(const void* p, int i, int isf32) {
  return isf32 ? ((const float*)p)[i] : __bfloat162float(((const bf16*)p)[i]);
}

// ---------------------------------------------------------------- prep (fused)
// Every block re-derives the dtype flag (scan of x as bf16 view), then handles
// its slice of: x convert, 5 weight transposes, 4 fc copies, stats zeroing.
static constexpr int PREP_TOTAL =
    (int)(N_XF + 192 + 4096 + 16384 + 65536 + 61440 + 16384 + 128 + 16384 + 128 + N_ZERO);

__global__ __launch_bounds__(256) void prep_kernel(
    const void* __restrict__ x, const void* __restrict__ W0, const void* __restrict__ W1,
    const void* __restrict__ W2, const void* __restrict__ W3, const void* __restrict__ Wh,
    const void* __restrict__ fc1w, const void* __restrict__ fc1b,
    const void* __restrict__ fc2w, const void* __restrict__ fc2b, float* __restrict__ ws) {
  __shared__ float red[256];
  const unsigned short* xr = (const unsigned short*)x;
  float mx = 0.f;
  for (int i = threadIdx.x; i < B * N * 3; i += 256) {
    float v = __uint_as_float(((unsigned)xr[i]) << 16);
    v = fabsf(v);
    if (!(v < 1e30f)) v = 1e30f;  // NaN/inf -> huge
    mx = fmaxf(mx, v);
  }
  red[threadIdx.x] = mx;
  __syncthreads();
  for (int s = 128; s > 0; s >>= 1) {
    if (threadIdx.x < s) red[threadIdx.x] = fmaxf(red[threadIdx.x], red[threadIdx.x + s]);
    __syncthreads();
  }
  int isf = red[0] > 1e3f ? 1 : 0;
  if (blockIdx.x == 0 && threadIdx.x == 0) ((int*)(ws + O_FLAG))[0] = isf;

  int idx = blockIdx.x * 256 + threadIdx.x;
  if (idx < (int)N_XF) { ws[O_XF + idx] = load_in(x, idx, isf); return; }
  idx -= (int)N_XF;
  if (idx < 192) {  // W0 [32][6] -> [6][32]
    int o = idx / 6, c = idx - o * 6;
    ws[O_WT0 + c * 32 + o] = load_in(W0, idx, isf);
    return;
  }
  idx -= 192;
  if (idx < 4096) {  // W1 [64][64]
    int o = idx >> 6, c = idx & 63;
    ws[O_WT1 + c * 64 + o] = load_in(W1, idx, isf);
    return;
  }
  idx -= 4096;
  if (idx < 16384) {  // W2 [128][128]
    int o = idx >> 7, c = idx & 127;
    ws[O_WT2 + c * 128 + o] = load_in(W2, idx, isf);
    return;
  }
  idx -= 16384;
  if (idx < 65536) {  // W3 [256][256]
    int o = idx >> 8, c = idx & 255;
    ws[O_WT3 + c * 256 + o] = load_in(W3, idx, isf);
    return;
  }
  idx -= 65536;
  if (idx < 61440) {  // Wh [128][480]
    int o = idx / 480, c = idx - o * 480;
    ws[O_WHT + c * 128 + o] = load_in(Wh, idx, isf);
    return;
  }
  idx -= 61440;
  if (idx < 16384) { ws[O_F1W + idx] = load_in(fc1w, idx, isf); return; }
  idx -= 16384;
  if (idx < 128) { ws[O_F1B + idx] = load_in(fc1b, idx, isf); return; }
  idx -= 128;
  if (idx < 16384) { ws[O_F2W + idx] = load_in(fc2w, idx, isf); return; }
  idx -= 16384;
  if (idx < 128) { ws[O_F2B + idx] = load_in(fc2b, idx, isf); return; }
  idx -= 128;
  if (idx < (int)N_ZERO) ws[O_CS0 + idx] = 0.f;
}

// ---------------------------------------------------------------- dist (sq fused)
// 128x128 tile per block, 8x8 per thread; row-square-norms accumulated from the
// staged LDS tiles (same c-order as a serial loop -> bit-identical distances).
template <int C>
__global__ __launch_bounds__(256) void dist_kernel(const float* __restrict__ h, int hstride,
                                                   float* __restrict__ dist) {
  constexpr int CW = 16;
  __shared__ float Ast[CW][132];
  __shared__ float Bst[CW][132];
  __shared__ float sqn[128], sqm[128];
  int b = blockIdx.z;
  int n0 = blockIdx.y * 128, m0 = blockIdx.x * 128;
  int tid = threadIdx.x;
  int tx = tid & 15, ty = tid >> 4;
  int rr = tid & 127;
  float dot[8][8] = {};
  float sqacc = 0.f;
  for (int cc = 0; cc < C; cc += CW) {
    for (int i = tid; i < 128 * CW; i += 256) {
      int c = i & 15, r = i >> 4;
      int gc = cc + c;
      float av = 0.f, bv = 0.f;
      if (gc < C) {
        av = h[(size_t)(b * N + n0 + r) * hstride + gc];
        bv = h[(size_t)(b * N + m0 + r) * hstride + gc];
      }
      Ast[c][r] = av;
      Bst[c][r] = bv;
    }
    __syncthreads();
    // row-norm partials from staged tiles
    if (tid < 128) {
#pragma unroll
      for (int c = 0; c < CW; ++c) { float v = Ast[c][rr]; sqacc += v * v; }
    } else {
#pragma unroll
      for (int c = 0; c < CW; ++c) { float v = Bst[c][rr]; sqacc += v * v; }
    }
#pragma unroll
    for (int c = 0; c < CW; ++c) {
      float4 a0 = *reinterpret_cast<const float4*>(&Ast[c][ty * 8]);
      float4 a1 = *reinterpret_cast<const float4*>(&Ast[c][ty * 8 + 4]);
      float4 b0 = *reinterpret_cast<const float4*>(&Bst[c][tx * 8]);
      float4 b1 = *reinterpret_cast<const float4*>(&Bst[c][tx * 8 + 4]);
      float av[8] = {a0.x, a0.y, a0.z, a0.w, a1.x, a1.y, a1.z, a1.w};
      float bv[8] = {b0.x, b0.y, b0.z, b0.w, b1.x, b1.y, b1.z, b1.w};
#pragma unroll
      for (int i = 0; i < 8; ++i)
#pragma unroll
        for (int j = 0; j < 8; ++j) dot[i][j] += av[i] * bv[j];
    }
    __syncthreads();
  }
  if (tid < 128) sqn[rr] = sqacc; else sqm[rr] = sqacc;
  __syncthreads();
#pragma unroll
  for (int i = 0; i < 8; ++i) {
    int nn = n0 + ty * 8 + i;
    float sn = sqn[ty * 8 + i];
#pragma unroll
    for (int jq = 0; jq < 2; ++jq) {
      float4 w;
      w.x = sn + sqm[tx * 8 + jq * 4 + 0] - 2.f * dot[i][jq * 4 + 0];
      w.y = sn + sqm[tx * 8 + jq * 4 + 1] - 2.f * dot[i][jq * 4 + 1];
      w.z = sn + sqm[tx * 8 + jq * 4 + 2] - 2.f * dot[i][jq * 4 + 2];
      w.w = sn + sqm[tx * 8 + jq * 4 + 3] - 2.f * dot[i][jq * 4 + 3];
      *reinterpret_cast<float4*>(&dist[(size_t)(b * N + nn) * N + m0 + tx * 8 + jq * 4]) = w;
    }
  }
}

__device__ __forceinline__ unsigned long long wave_min_u64(unsigned long long v) {
#pragma unroll
  for (int m = 1; m < 64; m <<= 1) {
    unsigned lo = (unsigned)v;
    unsigned hi = (unsigned)(v >> 32);
    unsigned olo = (unsigned)__shfl_xor((int)lo, m, 64);
    unsigned ohi = (unsigned)__shfl_xor((int)hi, m, 64);
    unsigned long long ov = ((unsigned long long)ohi << 32) | olo;
    if (ov < v) v = ov;
  }
  return v;
}

// One wave per row: lane caches 32 keys in registers, 33 extract-min rounds.
__global__ __launch_bounds__(256) void select_kernel(const float* __restrict__ dist,
                                                     int* __restrict__ idxb) {
  int row = blockIdx.x * 4 + (threadIdx.x >> 6);  // b*N + n
  int lane = threadIdx.x & 63;
  const float* drow = dist + (size_t)row * N;
  unsigned long long key[32];
#pragma unroll
  for (int j = 0; j < 32; ++j) {
    int m = j * 64 + lane;
    unsigned u = __float_as_uint(drow[m]);
    u = (u & 0x80000000u) ? ~u : (u | 0x80000000u);
    key[j] = ((unsigned long long)u << 32) | (unsigned)m;
  }
  unsigned long long lmin = key[0];
#pragma unroll
  for (int j = 1; j < 32; ++j) lmin = key[j] < lmin ? key[j] : lmin;
  unsigned saved = 0;
  for (int it = 0; it <= KNN; ++it) {
    unsigned long long gmin = wave_min_u64(lmin);
    if (it > 0 && lane == it - 1) saved = (unsigned)(gmin & 0xFFFFFFFFull);
    if (lmin == gmin) {  // unique keys -> exactly one winner lane
#pragma unroll
      for (int j = 0; j < 32; ++j)
        if (key[j] == gmin) key[j] = ~0ull;
      lmin = key[0];
#pragma unroll
      for (int j = 1; j < 32; ++j) lmin = key[j] < lmin ? key[j] : lmin;
    }
  }
  if (lane < KNN) idxb[row * KNN + lane] = (int)saved;
}

// ---------------------------------------------------------------- edge conv (fused)
// e[k][o] = sum_c Wd[c][o]*(nbr[k][c]-cen[c]) + sigma[o]; sigma = Wc^T cen.
// Thread: OT=O/32 outputs x 4 k (k = 8j+ko). nbr + W-chunk staged in LDS.
// No address-taking of register arrays (spill hazard, R5 post-mortem).
template <int C, int O>
__global__ __launch_bounds__(256) void edge_kernel(const float* __restrict__ h, int hstride,
                                                   const int* __restrict__ idxb,
                                                   const float* __restrict__ Wt,  // [2C][O]
                                                   float* __restrict__ cstats,    // [B*O*2]
                                                   float* __restrict__ featdst) { // feats col slice
  constexpr int OT = O / 32;
  constexpr int KC = (C >= 32) ? 32 : C;
  constexpr int CP = (C % 4 == 0) ? C + 4 : C;
  constexpr int OP = O + 4;
  int bn = blockIdx.x;
  int b = bn >> 11;
  int tid = threadIdx.x;
  int ko = tid & 7;
  int og = tid >> 3;
  int o0 = og * OT;

  __shared__ __align__(16) float nbr[KNN][CP];
  __shared__ __align__(16) float wlds[KC][OP];
  __shared__ float cen[C];
  __shared__ int knn[KNN];

  const float* hrow = h + (size_t)bn * hstride;
  if (tid < C) cen[tid] = hrow[tid];
  if (tid < KNN) knn[tid] = idxb[bn * KNN + tid];
  __syncthreads();
  for (int i = tid; i < KNN * C; i += 256) {
    int k = i / C, c = i - k * C;
    nbr[k][c] = h[(size_t)(b * N + knn[k]) * hstride + c] - cen[c];
  }

  // sigma[ot] = sum_c Wt[C+c][o0+ot] * cen[c], cooperative over 8 ko lanes
  float sig[OT] = {};
  for (int c = ko; c < C; c += 8) {
    float cv = cen[c];
    const float* wrow = Wt + (size_t)(C + c) * O + o0;
#pragma unroll
    for (int ot = 0; ot < OT; ++ot) sig[ot] += wrow[ot] * cv;
  }
#pragma unroll
  for (int ot = 0; ot < OT; ++ot) {
    sig[ot] += __shfl_xor(sig[ot], 1, 64);
    sig[ot] += __shfl_xor(sig[ot], 2, 64);
    sig[ot] += __shfl_xor(sig[ot], 4, 64);
  }

  float acc[4][OT];
#pragma unroll
  for (int j = 0; j < 4; ++j)
#pragma unroll
    for (int ot = 0; ot < OT; ++ot) acc[j][ot] = sig[ot];

  for (int c0 = 0; c0 < C; c0 += KC) {
    __syncthreads();  // nbr ready (iter 0) / previous chunk consumed
    for (int i = tid; i < KC * O; i += 256) {
      int r = i / O, cc = i - r * O;
      wlds[r][cc] = Wt[(size_t)(c0 + r) * O + cc];
    }
    __syncthreads();
    if constexpr (C % 4 == 0) {
#pragma unroll
      for (int cq = 0; cq < KC; cq += 4) {
        float4 v0 = *reinterpret_cast<const float4*>(&nbr[ko][c0 + cq]);
        float4 v1 = *reinterpret_cast<const float4*>(&nbr[8 + ko][c0 + cq]);
        float4 v2 = *reinterpret_cast<const float4*>(&nbr[16 + ko][c0 + cq]);
        float4 v3 = *reinterpret_cast<const float4*>(&nbr[24 + ko][c0 + cq]);
        float va[4][4] = {{v0.x, v0.y, v0.z, v0.w},
                          {v1.x, v1.y, v1.z, v1.w},
                          {v2.x, v2.y, v2.z, v2.w},
                          {v3.x, v3.y, v3.z, v3.w}};
#pragma unroll
        for (int i = 0; i < 4; ++i) {
          float w[OT];
          if constexpr (OT == 8) {
            float4 w0 = *reinterpret_cast<const float4*>(&wlds[cq + i][o0]);
            float4 w1 = *reinterpret_cast<const float4*>(&wlds[cq + i][o0 + 4]);
            w[0] = w0.x; w[1] = w0.y; w[2] = w0.z; w[3] = w0.w;
            w[4] = w1.x; w[5] = w1.y; w[6] = w1.z; w[7] = w1.w;
          } else if constexpr (OT == 4) {
            float4 w0 = *reinterpret_cast<const float4*>(&wlds[cq + i][o0]);
            w[0] = w0.x; w[1] = w0.y; w[2] = w0.z; w[3] = w0.w;
          } else {
#pragma unroll
            for (int ot = 0; ot < OT; ++ot) w[ot] = wlds[cq + i][o0 + ot];
          }
#pragma unroll
          for (int j = 0; j < 4; ++j)
#pragma unroll
            for (int ot = 0; ot < OT; ++ot) acc[j][ot] += w[ot] * va[j][i];
        }
      }
    } else {
      for (int c = 0; c < KC; ++c) {
        float w[OT];
#pragma unroll
        for (int ot = 0; ot < OT; ++ot) w[ot] = wlds[c][o0 + ot];
        float x0 = nbr[ko][c0 + c];
        float x1 = nbr[8 + ko][c0 + c];
        float x2 = nbr[16 + ko][c0 + c];
        float x3 = nbr[24 + ko][c0 + c];
#pragma unroll
        for (int ot = 0; ot < OT; ++ot) {
          acc[0][ot] += w[ot] * x0;
          acc[1][ot] += w[ot] * x1;
          acc[2][ot] += w[ot] * x2;
          acc[3][ot] += w[ot] * x3;
        }
      }
    }
  }

#pragma unroll
  for (int ot = 0; ot < OT; ++ot) {
    float s = 0.f, ss = 0.f, mx = -3.4e38f;
#pragma unroll
    for (int j = 0; j < 4; ++j) {
      float e = acc[j][ot];
      s += e;
      ss += e * e;
      mx = fmaxf(mx, e);
    }
#pragma unroll
    for (int m = 1; m < 8; m <<= 1) {
      s += __shfl_xor(s, m, 64);
      ss += __shfl_xor(ss, m, 64);
      mx = fmaxf(mx, __shfl_xor(mx, m, 64));
    }
    if (ko == 0) {
      atomicAdd(&cstats[(b * O + o0 + ot) * 2 + 0], s);
      atomicAdd(&cstats[(b * O + o0 + ot) * 2 + 1], ss);
      featdst[(size_t)bn * FD + o0 + ot] = mx;
    }
  }
}

// in-place: featdst = lrelu((featdst - mean) * rsqrt(var + eps))
__global__ void finalize_kernel(const float* __restrict__ cstats,
                                float* __restrict__ featdst, int O) {
  int i = blockIdx.x * 256 + threadIdx.x;  // (b*N+n)*O + o
  int o = i % O;
  int bn = i / O;
  int b = bn >> 11;
  float s = cstats[(b * O + o) * 2 + 0];
  float ss = cstats[(b * O + o) * 2 + 1];
  constexpr float inv = 1.f / ((float)N * KNN);
  float m = s * inv;
  float v = fmaxf(ss * inv - m * m, 0.f);
  float* p = &featdst[(size_t)bn * FD + o];
  float e = (*p - m) * rsqrtf(v + EPS);
  *p = lrelu(e);
}

// ---------------------------------------------------------------- 480 -> 128 stage
__global__ __launch_bounds__(256) void fstage_kernel(const float* __restrict__ feats,
                                                     const float* __restrict__ Wht,  // [480][128]
                                                     float* __restrict__ fsum,
                                                     float* __restrict__ fss,
                                                     unsigned* __restrict__ fmaxu) {
  int blk = blockIdx.x;
  int b = blk >> 7;
  int n0 = (blk & 127) * 16;
  int tid = threadIdx.x;
  __shared__ float rows[16][FD];
  __shared__ float red[3][2][128];
  for (int i = tid; i < 16 * FD; i += 256) {
    int r = i / FD, c = i - r * FD;
    rows[r][c] = feats[(size_t)(b * N + n0 + r) * FD + c];
  }
  __syncthreads();
  int o = tid & 127, g = tid >> 7;
  float acc[8] = {};
  for (int c = 0; c < FD; ++c) {
    float w = Wht[c * 128 + o];
#pragma unroll
    for (int j = 0; j < 8; ++j) acc[j] += w * rows[g * 8 + j][c];
  }
  float s = 0.f, ss = 0.f, mx = -3.4e38f;
#pragma unroll
  for (int j = 0; j < 8; ++j) {
    float f = acc[j];
    s += f;
    ss += f * f;
    mx = fmaxf(mx, f);
  }
  red[0][g][o] = s;
  red[1][g][o] = ss;
  red[2][g][o] = mx;
  __syncthreads();
  if (g == 0) {
    s += red[0][1][o];
    ss += red[1][1][o];
    mx = fmaxf(mx, red[2][1][o]);
    atomicAdd(&fsum[b * 128 + o], s);
    atomicAdd(&fss[b * 128 + o], ss);
    unsigned u = __float_as_uint(mx);
    u = (u & 0x80000000u) ? ~u : (u | 0x80000000u);
    atomicMax(&fmaxu[b * 128 + o], u);
  }
}

// ---------------------------------------------------------------- head
__global__ __launch_bounds__(128) void head_kernel(const float* __restrict__ fsum,
                                                   const float* __restrict__ fss,
                                                   const unsigned* __restrict__ fmaxu,
                                                   const float* __restrict__ fc1w,
                                                   const float* __restrict__ fc1b,
                                                   const float* __restrict__ fc2w,
                                                   const float* __restrict__ fc2b,
                                                   void* __restrict__ out,
                                                   const int* __restrict__ flag) {
  int b = blockIdx.x, o = threadIdx.x;
  __shared__ float gs[128], t1[128], ys[128];
  constexpr float invN = 1.f / N;
  float m = fsum[b * 128 + o] * invN;
  float v = fmaxf(fss[b * 128 + o] * invN - m * m, 0.f);
  unsigned u = fmaxu[b * 128 + o];
  unsigned bits = (u & 0x80000000u) ? (u ^ 0x80000000u) : ~u;
  float fx = __uint_as_float(bits);
  gs[o] = lrelu((fx - m) * rsqrtf(v + EPS));
  __syncthreads();
  float a = fc1b[o];
  for (int c = 0; c < 128; ++c) a += fc1w[o * 128 + c] * gs[c];
  t1[o] = a;
  __syncthreads();
  float mm = 0.f;
  for (int c = 0; c < 128; ++c) mm += t1[c];
  mm *= (1.f / 128);
  float vv = 0.f;
  for (int c = 0; c < 128; ++c) {
    float d = t1[c] - mm;
    vv += d * d;
  }
  vv *= (1.f / 128);
  ys[o] = lrelu((a - mm) * rsqrtf(vv + EPS));
  __syncthreads();
  float r = fc2b[o];
  for (int c = 0; c < 128; ++c) r += fc2w[o * 128 + c] * ys[c];
  if (flag[0])
    ((float*)out)[b * 128 + o] = r;
  else
    ((bf16*)out)[b * 128 + o] = __float2bfloat16(r);
}

// ---------------------------------------------------------------- driver
template <int C, int O>
static void run_layer(const float* h, int hstride, float* featdst, const float* Wt,
                      float* cstats, float* dist, int* idxb, hipStream_t stream) {
  dist_kernel<C><<<dim3(N / 128, N / 128, B), 256, 0, stream>>>(h, hstride, dist);
  select_kernel<<<B * N / 4, 256, 0, stream>>>(dist, idxb);
  edge_kernel<C, O><<<B * N, 256, 0, stream>>>(h, hstride, idxb, Wt, cstats, featdst);
  finalize_kernel<<<B * N * O / 256, 256, 0, stream>>>(cstats, featdst, O);
}

extern "C" void kernel_launch(void* const* d_in, const int* in_sizes, int n_in,
                              void* d_out, int out_size, void* d_ws, size_t ws_size,
                              hipStream_t stream) {
  float* ws = (float*)d_ws;
  float* xf = ws + O_XF;
  float* feats = ws + O_FEATS;
  float* dist = ws + O_DIST;
  int* idxb = (int*)(ws + O_IDX);
  int* flag = (int*)(ws + O_FLAG);

  prep_kernel<<<(PREP_TOTAL + 255) / 256, 256, 0, stream>>>(
      d_in[0], d_in[2], d_in[3], d_in[4], d_in[5], d_in[6], d_in[7], d_in[8], d_in[9],
      d_in[10], ws);

  run_layer<3, 32>(xf, 3, feats + 0, ws + O_WT0, ws + O_CS0, dist, idxb, stream);
  run_layer<32, 64>(feats + 0, FD, feats + 32, ws + O_WT1, ws + O_CS1, dist, idxb, stream);
  run_layer<64, 128>(feats + 32, FD, feats + 96, ws + O_WT2, ws + O_CS2, dist, idxb, stream);
  run_layer<128, 256>(feats + 96, FD, feats + 224, ws + O_WT3, ws + O_CS3, dist, idxb, stream);

  fstage_kernel<<<B * 128, 256, 0, stream>>>(feats, ws + O_WHT, ws + O_FSUM, ws + O_FSS,
                                             (unsigned*)(ws + O_FMAX));
  head_kernel<<<B, 128, 0, stream>>>(ws + O_FSUM, ws + O_FSS, (unsigned*)(ws + O_FMAX),
                                     ws + O_F1W, ws + O_F1B, ws + O_F2W, ws + O_F2B, d_out,
                                     flag);
}

// Round 7
// 1732.995 us; speedup vs baseline: 1.9464x; 1.8703x over previous
//
#include <hip/hip_runtime.h>
#include <hip/hip_bf16.h>
#include <cstdint>

using bf16 = __hip_bfloat16;

static constexpr int B = 2;
static constexpr int N = 2048;
static constexpr int KNN = 32;
static constexpr int FD = 480;
static constexpr float EPS = 1e-5f;
static constexpr float SLOPE = 0.2f;

// ---------------- workspace layout (floats), all compile-time ----------------
static constexpr size_t N_XF = (size_t)B * N * 3;
static constexpr size_t N_FEATS = (size_t)B * N * FD;
static constexpr size_t N_DIST = (size_t)B * N * N;
static constexpr size_t N_IDX = (size_t)B * N * KNN;
static constexpr size_t O_XF = 0;
static constexpr size_t O_FEATS = O_XF + N_XF;
static constexpr size_t O_DIST = O_FEATS + N_FEATS;
static constexpr size_t O_IDX = O_DIST + N_DIST;
static constexpr size_t O_WT0 = O_IDX + N_IDX;
static constexpr size_t O_WT1 = O_WT0 + 192;
static constexpr size_t O_WT2 = O_WT1 + 4096;
static constexpr size_t O_WT3 = O_WT2 + 16384;
static constexpr size_t O_WHT = O_WT3 + 65536;
static constexpr size_t O_F1W = O_WHT + 61440;
static constexpr size_t O_F1B = O_F1W + 16384;
static constexpr size_t O_F2W = O_F1B + 128;
static constexpr size_t O_F2B = O_F2W + 16384;
static constexpr size_t O_FLAG = O_F2B + 128;
static constexpr size_t O_CS0 = O_FLAG + 16;   // zero region starts here
static constexpr size_t O_CS1 = O_CS0 + 128;
static constexpr size_t O_CS2 = O_CS1 + 256;
static constexpr size_t O_CS3 = O_CS2 + 512;
static constexpr size_t O_FSUM = O_CS3 + 1024;
static constexpr size_t O_FSS = O_FSUM + 256;
static constexpr size_t O_FMAX = O_FSS + 256;
static constexpr size_t O_END = O_FMAX + 256;
static constexpr size_t N_ZERO = O_END - O_CS0;

__device__ __forceinline__ float lrelu(float x) { return x >= 0.f ? x : SLOPE * x; }

__device__ __forceinline__ float load_in(const void* p, int i, int isf32) {
  return isf32 ? ((const float*)p)[i] : __bfloat162float(((const bf16*)p)[i]);
}

// ---------------------------------------------------------------- prep (fused)
static constexpr int PREP_TOTAL =
    (int)(N_XF + 192 + 4096 + 16384 + 65536 + 61440 + 16384 + 128 + 16384 + 128 + N_ZERO);

__global__ __launch_bounds__(256) void prep_kernel(
    const void* __restrict__ x, const void* __restrict__ W0, const void* __restrict__ W1,
    const void* __restrict__ W2, const void* __restrict__ W3, const void* __restrict__ Wh,
    const void* __restrict__ fc1w, const void* __restrict__ fc1b,
    const void* __restrict__ fc2w, const void* __restrict__ fc2b, float* __restrict__ ws) {
  __shared__ float red[256];
  const unsigned short* xr = (const unsigned short*)x;
  float mx = 0.f;
  for (int i = threadIdx.x; i < B * N * 3; i += 256) {
    float v = __uint_as_float(((unsigned)xr[i]) << 16);
    v = fabsf(v);
    if (!(v < 1e30f)) v = 1e30f;  // NaN/inf -> huge
    mx = fmaxf(mx, v);
  }
  red[threadIdx.x] = mx;
  __syncthreads();
  for (int s = 128; s > 0; s >>= 1) {
    if (threadIdx.x < s) red[threadIdx.x] = fmaxf(red[threadIdx.x], red[threadIdx.x + s]);
    __syncthreads();
  }
  int isf = red[0] > 1e3f ? 1 : 0;
  if (blockIdx.x == 0 && threadIdx.x == 0) ((int*)(ws + O_FLAG))[0] = isf;

  int idx = blockIdx.x * 256 + threadIdx.x;
  if (idx < (int)N_XF) { ws[O_XF + idx] = load_in(x, idx, isf); return; }
  idx -= (int)N_XF;
  if (idx < 192) {
    int o = idx / 6, c = idx - o * 6;
    ws[O_WT0 + c * 32 + o] = load_in(W0, idx, isf);
    return;
  }
  idx -= 192;
  if (idx < 4096) {
    int o = idx >> 6, c = idx & 63;
    ws[O_WT1 + c * 64 + o] = load_in(W1, idx, isf);
    return;
  }
  idx -= 4096;
  if (idx < 16384) {
    int o = idx >> 7, c = idx & 127;
    ws[O_WT2 + c * 128 + o] = load_in(W2, idx, isf);
    return;
  }
  idx -= 16384;
  if (idx < 65536) {
    int o = idx >> 8, c = idx & 255;
    ws[O_WT3 + c * 256 + o] = load_in(W3, idx, isf);
    return;
  }
  idx -= 65536;
  if (idx < 61440) {
    int o = idx / 480, c = idx - o * 480;
    ws[O_WHT + c * 128 + o] = load_in(Wh, idx, isf);
    return;
  }
  idx -= 61440;
  if (idx < 16384) { ws[O_F1W + idx] = load_in(fc1w, idx, isf); return; }
  idx -= 16384;
  if (idx < 128) { ws[O_F1B + idx] = load_in(fc1b, idx, isf); return; }
  idx -= 128;
  if (idx < 16384) { ws[O_F2W + idx] = load_in(fc2w, idx, isf); return; }
  idx -= 16384;
  if (idx < 128) { ws[O_F2B + idx] = load_in(fc2b, idx, isf); return; }
  idx -= 128;
  if (idx < (int)N_ZERO) ws[O_CS0 + idx] = 0.f;
}

// ---------------------------------------------------------------- dist (sq fused)
// 128x128 tile, 8x8 per thread. Scalar LDS reads into 1-D arrays (R4-proven
// idiom: constant-index only, no float4->array, no address-taking).
template <int C>
__global__ __launch_bounds__(256) void dist_kernel(const float* __restrict__ h, int hstride,
                                                   float* __restrict__ dist) {
  constexpr int CW = 16;
  __shared__ float Ast[CW][132];
  __shared__ float Bst[CW][132];
  __shared__ float sqn[128], sqm[128];
  int b = blockIdx.z;
  int n0 = blockIdx.y * 128, m0 = blockIdx.x * 128;
  int tid = threadIdx.x;
  int tx = tid & 15, ty = tid >> 4;
  int rr = tid & 127;
  float dot[8][8] = {};
  float sqacc = 0.f;
  for (int cc = 0; cc < C; cc += CW) {
    for (int i = tid; i < 128 * CW; i += 256) {
      int c = i & 15, r = i >> 4;
      int gc = cc + c;
      float av = 0.f, bv = 0.f;
      if (gc < C) {
        av = h[(size_t)(b * N + n0 + r) * hstride + gc];
        bv = h[(size_t)(b * N + m0 + r) * hstride + gc];
      }
      Ast[c][r] = av;
      Bst[c][r] = bv;
    }
    __syncthreads();
    if (tid < 128) {
#pragma unroll
      for (int c = 0; c < CW; ++c) { float v = Ast[c][rr]; sqacc += v * v; }
    } else {
#pragma unroll
      for (int c = 0; c < CW; ++c) { float v = Bst[c][rr]; sqacc += v * v; }
    }
#pragma unroll
    for (int c = 0; c < CW; ++c) {
      float av[8], bv[8];
#pragma unroll
      for (int i = 0; i < 8; ++i) av[i] = Ast[c][ty * 8 + i];
#pragma unroll
      for (int j = 0; j < 8; ++j) bv[j] = Bst[c][tx * 8 + j];
#pragma unroll
      for (int i = 0; i < 8; ++i)
#pragma unroll
        for (int j = 0; j < 8; ++j) dot[i][j] += av[i] * bv[j];
    }
    __syncthreads();
  }
  if (tid < 128) sqn[rr] = sqacc; else sqm[rr] = sqacc;
  __syncthreads();
#pragma unroll
  for (int i = 0; i < 8; ++i) {
    int nn = n0 + ty * 8 + i;
    float sn = sqn[ty * 8 + i];
#pragma unroll
    for (int jq = 0; jq < 2; ++jq) {
      float4 w;
      w.x = sn + sqm[tx * 8 + jq * 4 + 0] - 2.f * dot[i][jq * 4 + 0];
      w.y = sn + sqm[tx * 8 + jq * 4 + 1] - 2.f * dot[i][jq * 4 + 1];
      w.z = sn + sqm[tx * 8 + jq * 4 + 2] - 2.f * dot[i][jq * 4 + 2];
      w.w = sn + sqm[tx * 8 + jq * 4 + 3] - 2.f * dot[i][jq * 4 + 3];
      *reinterpret_cast<float4*>(&dist[(size_t)(b * N + nn) * N + m0 + tx * 8 + jq * 4]) = w;
    }
  }
}

__device__ __forceinline__ unsigned long long wave_min_u64(unsigned long long v) {
#pragma unroll
  for (int m = 1; m < 64; m <<= 1) {
    unsigned lo = (unsigned)v;
    unsigned hi = (unsigned)(v >> 32);
    unsigned olo = (unsigned)__shfl_xor((int)lo, m, 64);
    unsigned ohi = (unsigned)__shfl_xor((int)hi, m, 64);
    unsigned long long ov = ((unsigned long long)ohi << 32) | olo;
    if (ov < v) v = ov;
  }
  return v;
}

// One wave per row: lane caches 32 keys in registers, 33 extract-min rounds.
__global__ __launch_bounds__(256) void select_kernel(const float* __restrict__ dist,
                                                     int* __restrict__ idxb) {
  int row = blockIdx.x * 4 + (threadIdx.x >> 6);  // b*N + n
  int lane = threadIdx.x & 63;
  const float* drow = dist + (size_t)row * N;
  unsigned long long key[32];
#pragma unroll
  for (int j = 0; j < 32; ++j) {
    int m = j * 64 + lane;
    unsigned u = __float_as_uint(drow[m]);
    u = (u & 0x80000000u) ? ~u : (u | 0x80000000u);
    key[j] = ((unsigned long long)u << 32) | (unsigned)m;
  }
  unsigned long long lmin = key[0];
#pragma unroll
  for (int j = 1; j < 32; ++j) lmin = key[j] < lmin ? key[j] : lmin;
  unsigned saved = 0;
  for (int it = 0; it <= KNN; ++it) {
    unsigned long long gmin = wave_min_u64(lmin);
    if (it > 0 && lane == it - 1) saved = (unsigned)(gmin & 0xFFFFFFFFull);
    if (lmin == gmin) {
#pragma unroll
      for (int j = 0; j < 32; ++j)
        if (key[j] == gmin) key[j] = ~0ull;
      lmin = key[0];
#pragma unroll
      for (int j = 1; j < 32; ++j) lmin = key[j] < lmin ? key[j] : lmin;
    }
  }
  if (lane < KNN) idxb[row * KNN + lane] = (int)saved;
}

// ---------------------------------------------------------------- edge conv (fused)
// R4-proven version (254 us @ layer4, VALU 77%): o per thread, KPG neighbors,
// scalar weight loads from global, float4 nbr reads via .x/.y/.z/.w only.
template <int C, int O>
__global__ __launch_bounds__(256) void edge_kernel(const float* __restrict__ h, int hstride,
                                                   const int* __restrict__ idxb,
                                                   const float* __restrict__ Wt,  // [2C][O]
                                                   float* __restrict__ cstats,    // [B*O*2]
                                                   float* __restrict__ featdst) { // feats col slice
  constexpr int KG = 256 / O;
  constexpr int KPG = KNN / KG;
  int bn = blockIdx.x;
  int b = bn >> 11;
  int tid = threadIdx.x;
  int o = tid % O;
  int kg = tid / O;

  __shared__ __align__(16) float nbr[KNN][C];
  __shared__ float cen[C];
  __shared__ int knn[KNN];
  __shared__ float red[3][KG][O];

  const float* hrow = h + (size_t)bn * hstride;
  if (tid < C) cen[tid] = hrow[tid];
  if (tid < KNN) knn[tid] = idxb[bn * KNN + tid];
  __syncthreads();
  for (int i = tid; i < KNN * C; i += 256) {
    int k = i / C, c = i - k * C;
    nbr[k][c] = h[(size_t)(b * N + knn[k]) * hstride + c];
  }
  __syncthreads();

  float ecen = 0.f;
  for (int c = 0; c < C; ++c)
    ecen += (Wt[(C + c) * O + o] - Wt[c * O + o]) * cen[c];

  float acc[KPG];
#pragma unroll
  for (int j = 0; j < KPG; ++j) acc[j] = ecen;

  if constexpr (C % 4 == 0) {
    for (int c = 0; c < C; c += 4) {
      float w0 = Wt[(c + 0) * O + o];
      float w1 = Wt[(c + 1) * O + o];
      float w2 = Wt[(c + 2) * O + o];
      float w3 = Wt[(c + 3) * O + o];
#pragma unroll
      for (int j = 0; j < KPG; ++j) {
        const float4 v = *reinterpret_cast<const float4*>(&nbr[kg * KPG + j][c]);
        acc[j] += w0 * v.x + w1 * v.y + w2 * v.z + w3 * v.w;
      }
    }
  } else {
    for (int c = 0; c < C; ++c) {
      float w = Wt[c * O + o];
#pragma unroll
      for (int j = 0; j < KPG; ++j) acc[j] += w * nbr[kg * KPG + j][c];
    }
  }

  float s = 0.f, ss = 0.f, mx = -3.4e38f;
#pragma unroll
  for (int j = 0; j < KPG; ++j) {
    float e = acc[j];
    s += e;
    ss += e * e;
    mx = fmaxf(mx, e);
  }

  if constexpr (KG > 1) {
    red[0][kg][o] = s;
    red[1][kg][o] = ss;
    red[2][kg][o] = mx;
    __syncthreads();
    if (kg == 0) {
#pragma unroll
      for (int g = 1; g < KG; ++g) {
        s += red[0][g][o];
        ss += red[1][g][o];
        mx = fmaxf(mx, red[2][g][o]);
      }
    }
  }
  if (kg == 0) {
    atomicAdd(&cstats[(b * O + o) * 2 + 0], s);
    atomicAdd(&cstats[(b * O + o) * 2 + 1], ss);
    featdst[(size_t)bn * FD + o] = mx;
  }
}

// in-place: featdst = lrelu((featdst - mean) * rsqrt(var + eps))
__global__ void finalize_kernel(const float* __restrict__ cstats,
                                float* __restrict__ featdst, int O) {
  int i = blockIdx.x * 256 + threadIdx.x;
  int o = i % O;
  int bn = i / O;
  int b = bn >> 11;
  float s = cstats[(b * O + o) * 2 + 0];
  float ss = cstats[(b * O + o) * 2 + 1];
  constexpr float inv = 1.f / ((float)N * KNN);
  float m = s * inv;
  float v = fmaxf(ss * inv - m * m, 0.f);
  float* p = &featdst[(size_t)bn * FD + o];
  float e = (*p - m) * rsqrtf(v + EPS);
  *p = lrelu(e);
}

// ---------------------------------------------------------------- 480 -> 128 stage
__global__ __launch_bounds__(256) void fstage_kernel(const float* __restrict__ feats,
                                                     const float* __restrict__ Wht,
                                                     float* __restrict__ fsum,
                                                     float* __restrict__ fss,
                                                     unsigned* __restrict__ fmaxu) {
  int blk = blockIdx.x;
  int b = blk >> 7;
  int n0 = (blk & 127) * 16;
  int tid = threadIdx.x;
  __shared__ float rows[16][FD];
  __shared__ float red[3][2][128];
  for (int i = tid; i < 16 * FD; i += 256) {
    int r = i / FD, c = i - r * FD;
    rows[r][c] = feats[(size_t)(b * N + n0 + r) * FD + c];
  }
  __syncthreads();
  int o = tid & 127, g = tid >> 7;
  float acc[8] = {};
  for (int c = 0; c < FD; ++c) {
    float w = Wht[c * 128 + o];
#pragma unroll
    for (int j = 0; j < 8; ++j) acc[j] += w * rows[g * 8 + j][c];
  }
  float s = 0.f, ss = 0.f, mx = -3.4e38f;
#pragma unroll
  for (int j = 0; j < 8; ++j) {
    float f = acc[j];
    s += f;
    ss += f * f;
    mx = fmaxf(mx, f);
  }
  red[0][g][o] = s;
  red[1][g][o] = ss;
  red[2][g][o] = mx;
  __syncthreads();
  if (g == 0) {
    s += red[0][1][o];
    ss += red[1][1][o];
    mx = fmaxf(mx, red[2][1][o]);
    atomicAdd(&fsum[b * 128 + o], s);
    atomicAdd(&fss[b * 128 + o], ss);
    unsigned u = __float_as_uint(mx);
    u = (u & 0x80000000u) ? ~u : (u | 0x80000000u);
    atomicMax(&fmaxu[b * 128 + o], u);
  }
}

// ---------------------------------------------------------------- head
__global__ __launch_bounds__(128) void head_kernel(const float* __restrict__ fsum,
                                                   const float* __restrict__ fss,
                                                   const unsigned* __restrict__ fmaxu,
                                                   const float* __restrict__ fc1w,
                                                   const float* __restrict__ fc1b,
                                                   const float* __restrict__ fc2w,
                                                   const float* __restrict__ fc2b,
                                                   void* __restrict__ out,
                                                   const int* __restrict__ flag) {
  int b = blockIdx.x, o = threadIdx.x;
  __shared__ float gs[128], t1[128], ys[128];
  constexpr float invN = 1.f / N;
  float m = fsum[b * 128 + o] * invN;
  float v = fmaxf(fss[b * 128 + o] * invN - m * m, 0.f);
  unsigned u = fmaxu[b * 128 + o];
  unsigned bits = (u & 0x80000000u) ? (u ^ 0x80000000u) : ~u;
  float fx = __uint_as_float(bits);
  gs[o] = lrelu((fx - m) * rsqrtf(v + EPS));
  __syncthreads();
  float a = fc1b[o];
  for (int c = 0; c < 128; ++c) a += fc1w[o * 128 + c] * gs[c];
  t1[o] = a;
  __syncthreads();
  float mm = 0.f;
  for (int c = 0; c < 128; ++c) mm += t1[c];
  mm *= (1.f / 128);
  float vv = 0.f;
  for (int c = 0; c < 128; ++c) {
    float d = t1[c] - mm;
    vv += d * d;
  }
  vv *= (1.f / 128);
  ys[o] = lrelu((a - mm) * rsqrtf(vv + EPS));
  __syncthreads();
  float r = fc2b[o];
  for (int c = 0; c < 128; ++c) r += fc2w[o * 128 + c] * ys[c];
  if (flag[0])
    ((float*)out)[b * 128 + o] = r;
  else
    ((bf16*)out)[b * 128 + o] = __float2bfloat16(r);
}

// ---------------------------------------------------------------- driver
template <int C, int O>
static void run_layer(const float* h, int hstride, float* featdst, const float* Wt,
                      float* cstats, float* dist, int* idxb, hipStream_t stream) {
  dist_kernel<C><<<dim3(N / 128, N / 128, B), 256, 0, stream>>>(h, hstride, dist);
  select_kernel<<<B * N / 4, 256, 0, stream>>>(dist, idxb);
  edge_kernel<C, O><<<B * N, 256, 0, stream>>>(h, hstride, idxb, Wt, cstats, featdst);
  finalize_kernel<<<B * N * O / 256, 256, 0, stream>>>(cstats, featdst, O);
}

extern "C" void kernel_launch(void* const* d_in, const int* in_sizes, int n_in,
                              void* d_out, int out_size, void* d_ws, size_t ws_size,
                              hipStream_t stream) {
  float* ws = (float*)d_ws;
  float* xf = ws + O_XF;
  float* feats = ws + O_FEATS;
  float* dist = ws + O_DIST;
  int* idxb = (int*)(ws + O_IDX);
  int* flag = (int*)(ws + O_FLAG);

  prep_kernel<<<(PREP_TOTAL + 255) / 256, 256, 0, stream>>>(
      d_in[0], d_in[2], d_in[3], d_in[4], d_in[5], d_in[6], d_in[7], d_in[8], d_in[9],
      d_in[10], ws);

  run_layer<3, 32>(xf, 3, feats + 0, ws + O_WT0, ws + O_CS0, dist, idxb, stream);
  run_layer<32, 64>(feats + 0, FD, feats + 32, ws + O_WT1, ws + O_CS1, dist, idxb, stream);
  run_layer<64, 128>(feats + 32, FD, feats + 96, ws + O_WT2, ws + O_CS2, dist, idxb, stream);
  run_layer<128, 256>(feats + 96, FD, feats + 224, ws + O_WT3, ws + O_CS3, dist, idxb, stream);

  fstage_kernel<<<B * 128, 256, 0, stream>>>(feats, ws + O_WHT, ws + O_FSUM, ws + O_FSS,
                                             (unsigned*)(ws + O_FMAX));
  head_kernel<<<B, 128, 0, stream>>>(ws + O_FSUM, ws + O_FSS, (unsigned*)(ws + O_FMAX),
                                     ws + O_F1W, ws + O_F1B, ws + O_F2W, ws + O_F2B, d_out,
                                     flag);
}